// Round 5
// baseline (497.015 us; speedup 1.0000x reference)
//
#include <hip/hip_runtime.h>
#include <math.h>

#define IN_FEATS 128
#define OUT_FEATS 64
#define NEG_SLOPE 0.2f
#define MAXD 256

// ---------------------------------------------------------------------------
// K1: h[n][o] = sum_k feat[n][k] * W[o][k]
// Wave = 64 nodes x 16 outputs. Output-quarter q = wid&3 is wave-uniform so
// W stays on the scalar path (s_load). Feat row is read in 4 k-chunks of 32
// floats (8 float4 regs) -> ~60 VGPRs -> 8 waves/SIMD. The 4 quarter-waves of
// a node group sit in the same block so their 64B store segments merge in L2.
// ---------------------------------------------------------------------------
__global__ __launch_bounds__(256)
void gemm_h_kernel(const float* __restrict__ feat,
                   const float* __restrict__ W,
                   float* __restrict__ h, int n_nodes) {
  const int wid  = (blockIdx.x * blockDim.x + threadIdx.x) >> 6;
  const int lane = threadIdx.x & 63;
  const int q    = wid & 3;                 // output quarter (wave-uniform)
  const int node = (wid >> 2) * 64 + lane;
  if (node >= n_nodes) return;

  const float* __restrict__ frow = feat + (size_t)node * IN_FEATS;
  const float* __restrict__ Wq   = W + (size_t)q * 16 * IN_FEATS;

  float acc[16];
#pragma unroll
  for (int o = 0; o < 16; ++o) acc[o] = 0.f;

#pragma unroll
  for (int c = 0; c < 4; ++c) {             // k-chunks of 32 floats
    float4 f[8];
    const float4* fv = reinterpret_cast<const float4*>(frow + c * 32);
#pragma unroll
    for (int j = 0; j < 8; ++j) f[j] = fv[j];
#pragma unroll
    for (int o = 0; o < 16; ++o) {
      const float* __restrict__ w = Wq + (size_t)o * IN_FEATS + c * 32;
      float a = acc[o];
#pragma unroll
      for (int j = 0; j < 8; ++j) {
        float4 fk = f[j];
        a = fmaf(fk.x, w[4*j+0], a);
        a = fmaf(fk.y, w[4*j+1], a);
        a = fmaf(fk.z, w[4*j+2], a);
        a = fmaf(fk.w, w[4*j+3], a);
      }
      acc[o] = a;
    }
  }

  float4* out = reinterpret_cast<float4*>(h + (size_t)node * OUT_FEATS + q * 16);
#pragma unroll
  for (int o4 = 0; o4 < 4; ++o4) {
    float4 v;
    v.x = acc[4*o4+0]; v.y = acc[4*o4+1]; v.z = acc[4*o4+2]; v.w = acc[4*o4+3];
    out[o4] = v;
  }
}

// ---------------------------------------------------------------------------
// CSR build: histogram -> 3-kernel exclusive scan -> bin (packed int2)
// ---------------------------------------------------------------------------
__global__ void hist_kernel(const int* __restrict__ dst, int* __restrict__ deg,
                            int n_edges) {
  int e = blockIdx.x * blockDim.x + threadIdx.x;
  if (e < n_edges) atomicAdd(&deg[dst[e]], 1);
}

__global__ void scan1_kernel(const int* __restrict__ deg, int* __restrict__ bsum,
                             int n) {
  __shared__ int tmp[256];
  int i = blockIdx.x * 256 + threadIdx.x;
  tmp[threadIdx.x] = (i < n) ? deg[i] : 0;
  __syncthreads();
  for (int off = 128; off > 0; off >>= 1) {
    if (threadIdx.x < off) tmp[threadIdx.x] += tmp[threadIdx.x + off];
    __syncthreads();
  }
  if (threadIdx.x == 0) bsum[blockIdx.x] = tmp[0];
}

__global__ void scan2_kernel(int* __restrict__ bsum, int nb) {
  __shared__ int tmp[1024];
  int t = threadIdx.x;
  int v = (t < nb) ? bsum[t] : 0;
  tmp[t] = v;
  __syncthreads();
  for (int off = 1; off < 1024; off <<= 1) {
    int x = (t >= off) ? tmp[t - off] : 0;
    __syncthreads();
    tmp[t] += x;
    __syncthreads();
  }
  if (t < nb) bsum[t] = tmp[t] - v;  // exclusive
}

__global__ void scan3_kernel(const int* __restrict__ deg, const int* __restrict__ bsum,
                             int* __restrict__ row_ptr, int* __restrict__ cursor,
                             int n, int n_edges) {
  __shared__ int tmp[256];
  int i = blockIdx.x * 256 + threadIdx.x;
  int v = (i < n) ? deg[i] : 0;
  tmp[threadIdx.x] = v;
  __syncthreads();
  for (int off = 1; off < 256; off <<= 1) {
    int x = (threadIdx.x >= off) ? tmp[threadIdx.x - off] : 0;
    __syncthreads();
    tmp[threadIdx.x] += x;
    __syncthreads();
  }
  if (i < n) {
    int excl = tmp[threadIdx.x] - v + bsum[blockIdx.x];
    row_ptr[i] = excl;
    cursor[i]  = excl;
  }
  if (i == 0) row_ptr[n] = n_edges;
}

__global__ void bin_kernel(const int* __restrict__ src, const int* __restrict__ dst,
                           int* __restrict__ cursor, int2* __restrict__ edata,
                           int n_edges) {
  int e = blockIdx.x * blockDim.x + threadIdx.x;
  if (e < n_edges) {
    int d = dst[e];
    int pos = atomicAdd(&cursor[d], 1);
    int2 v; v.x = src[e]; v.y = e;
    edata[pos] = v;
  }
}

// ---------------------------------------------------------------------------
// agg: wave per node, 4 edges in flight (lane = 16*eo + fo, float4 per lane)
// ---------------------------------------------------------------------------
__global__ void agg_kernel(const float* __restrict__ h, const int* __restrict__ row_ptr,
                           const int2* __restrict__ edata, float* __restrict__ h_agg,
                           int n_nodes) {
  int wid  = (blockIdx.x * blockDim.x + threadIdx.x) >> 6;
  int lane = threadIdx.x & 63;
  int eo = lane >> 4;   // edge slot in group of 4
  int fo = lane & 15;   // float4 slot in row
  if (wid >= n_nodes) return;
  int beg = row_ptr[wid], end = row_ptr[wid + 1];
  float4 acc = {0.f, 0.f, 0.f, 0.f};
  for (int i = beg + eo; i < end; i += 4) {
    int s = edata[i].x;
    float4 v = *reinterpret_cast<const float4*>(h + (size_t)s * OUT_FEATS + fo * 4);
    acc.x += v.x; acc.y += v.y; acc.z += v.z; acc.w += v.w;
  }
#pragma unroll
  for (int off = 16; off < 64; off <<= 1) {
    acc.x += __shfl_xor(acc.x, off, 64);
    acc.y += __shfl_xor(acc.y, off, 64);
    acc.z += __shfl_xor(acc.z, off, 64);
    acc.w += __shfl_xor(acc.w, off, 64);
  }
  if (eo == 0)
    *reinterpret_cast<float4*>(h_agg + (size_t)wid * OUT_FEATS + fo * 4) = acc;
}

// ---------------------------------------------------------------------------
// fused per-node edge softmax, 4 edges in flight.
// ---------------------------------------------------------------------------
__global__ __launch_bounds__(256)
void softmax_kernel(const float* __restrict__ h_agg, const int* __restrict__ row_ptr,
                    const int2* __restrict__ edata,
                    float* __restrict__ e_soft, int n_nodes) {
  __shared__ float ebuf[4][MAXD];
  int wid  = (blockIdx.x * blockDim.x + threadIdx.x) >> 6;
  int lane = threadIdx.x & 63;
  int lw   = threadIdx.x >> 6;
  int eo = lane >> 4;
  int fo = lane & 15;
  if (wid >= n_nodes) return;
  int beg = row_ptr[wid], end = row_ptr[wid + 1];
  int deg = end - beg;
  if (deg == 0) return;

  float4 td = *reinterpret_cast<const float4*>(h_agg + (size_t)wid * OUT_FEATS + fo * 4);
  float4 t4;
  t4.x = tanhf(td.x); t4.y = tanhf(td.y); t4.z = tanhf(td.z); t4.w = tanhf(td.w);

  if (deg <= MAXD) {
    for (int i0 = 0; i0 < deg; i0 += 4) {
      int e = i0 + eo;
      int idx = beg + (e < deg ? e : deg - 1);  // clamp; dup gather harmless
      int s = edata[idx].x;
      float4 v = *reinterpret_cast<const float4*>(h_agg + (size_t)s * OUT_FEATS + fo * 4);
      float d = v.x * t4.x + v.y * t4.y + v.z * t4.z + v.w * t4.w;
#pragma unroll
      for (int off = 1; off < 16; off <<= 1) d += __shfl_xor(d, off, 64);
      if (fo == 0 && e < deg) {
        d = d > 0.f ? d : NEG_SLOPE * d;
        ebuf[lw][e] = d;
      }
    }
    float mx = -INFINITY;
    for (int i = lane; i < deg; i += 64) mx = fmaxf(mx, ebuf[lw][i]);
#pragma unroll
    for (int off = 32; off > 0; off >>= 1) mx = fmaxf(mx, __shfl_xor(mx, off, 64));
    float sum = 0.f;
    for (int i = lane; i < deg; i += 64) {
      float ex = expf(ebuf[lw][i] - mx);
      ebuf[lw][i] = ex;
      sum += ex;
    }
#pragma unroll
    for (int off = 32; off > 0; off >>= 1) sum += __shfl_xor(sum, off, 64);
    float inv = 1.f / sum;
    for (int i = lane; i < deg; i += 64) e_soft[edata[beg + i].y] = ebuf[lw][i] * inv;
  } else {
    // recompute fallback (statistically never hit with Poisson(16) degrees)
    float mx = -INFINITY;
    for (int i0 = 0; i0 < deg; i0 += 4) {
      int e = i0 + eo;
      int idx = beg + (e < deg ? e : deg - 1);
      int s = edata[idx].x;
      float4 v = *reinterpret_cast<const float4*>(h_agg + (size_t)s * OUT_FEATS + fo * 4);
      float d = v.x * t4.x + v.y * t4.y + v.z * t4.z + v.w * t4.w;
#pragma unroll
      for (int off = 1; off < 16; off <<= 1) d += __shfl_xor(d, off, 64);
      d = d > 0.f ? d : NEG_SLOPE * d;
      if (e >= deg) d = -INFINITY;
#pragma unroll
      for (int off = 16; off < 64; off <<= 1) d = fmaxf(d, __shfl_xor(d, off, 64));
      mx = fmaxf(mx, d);
    }
    float sum = 0.f;
    for (int i0 = 0; i0 < deg; i0 += 4) {
      int e = i0 + eo;
      int idx = beg + (e < deg ? e : deg - 1);
      int s = edata[idx].x;
      float4 v = *reinterpret_cast<const float4*>(h_agg + (size_t)s * OUT_FEATS + fo * 4);
      float d = v.x * t4.x + v.y * t4.y + v.z * t4.z + v.w * t4.w;
#pragma unroll
      for (int off = 1; off < 16; off <<= 1) d += __shfl_xor(d, off, 64);
      d = d > 0.f ? d : NEG_SLOPE * d;
      float ex = (e < deg) ? expf(d - mx) : 0.f;
#pragma unroll
      for (int off = 16; off < 64; off <<= 1) ex += __shfl_xor(ex, off, 64);
      sum += ex;
    }
    float inv = 1.f / sum;
    for (int i0 = 0; i0 < deg; i0 += 4) {
      int e = i0 + eo;
      int idx = beg + (e < deg ? e : deg - 1);
      int s = edata[idx].x;
      float4 v = *reinterpret_cast<const float4*>(h_agg + (size_t)s * OUT_FEATS + fo * 4);
      float d = v.x * t4.x + v.y * t4.y + v.z * t4.z + v.w * t4.w;
#pragma unroll
      for (int off = 1; off < 16; off <<= 1) d += __shfl_xor(d, off, 64);
      d = d > 0.f ? d : NEG_SLOPE * d;
      if (fo == 0 && e < deg) e_soft[edata[idx].y] = expf(d - mx) * inv;
    }
  }
}

extern "C" void kernel_launch(void* const* d_in, const int* in_sizes, int n_in,
                              void* d_out, int out_size, void* d_ws, size_t ws_size,
                              hipStream_t stream) {
  const float* feat = (const float*)d_in[0];
  const float* W    = (const float*)d_in[1];
  const int*   src  = (const int*)d_in[2];
  const int*   dst  = (const int*)d_in[3];
  const int n_nodes = in_sizes[0] / IN_FEATS;
  const int n_edges = in_sizes[2];

  // Output layout: [h_agg (N*64) | e_soft (E)]
  float* h_agg  = (float*)d_out;
  float* e_soft = (float*)d_out + (size_t)n_nodes * OUT_FEATS;

  // Workspace: [h (N*64 f32) | deg (N) | row_ptr (N+1) | cursor (N) | bsum (1024) | edata (2*E ints)]
  float* h      = (float*)d_ws;
  int* deg      = (int*)(h + (size_t)n_nodes * OUT_FEATS);
  int* row_ptr  = deg + n_nodes;
  int* cursor   = row_ptr + (n_nodes + 1);
  int* bsum     = cursor + n_nodes;
  int2* edata   = (int2*)(bsum + 1024);

  const int nb = (n_nodes + 255) / 256;   // 391 blocks; scan2 handles nb<=1024
  const int eb = (n_edges + 255) / 256;
  const int wb = (n_nodes * 64 + 255) / 256;  // wave-per-node grids

  hipMemsetAsync(deg, 0, (size_t)n_nodes * sizeof(int), stream);

  // gemm: 4 waves per 64-node group (one per output quarter)
  const int ngroups = (n_nodes + 63) / 64;
  const int gemm_waves = ngroups * 4;
  const int gemm_blocks = (gemm_waves + 3) / 4;   // 4 waves per block
  gemm_h_kernel<<<gemm_blocks, 256, 0, stream>>>(feat, W, h, n_nodes);

  hist_kernel<<<eb, 256, 0, stream>>>(dst, deg, n_edges);
  scan1_kernel<<<nb, 256, 0, stream>>>(deg, bsum, n_nodes);
  scan2_kernel<<<1, 1024, 0, stream>>>(bsum, nb);
  scan3_kernel<<<nb, 256, 0, stream>>>(deg, bsum, row_ptr, cursor, n_nodes, n_edges);
  bin_kernel<<<eb, 256, 0, stream>>>(src, dst, cursor, edata, n_edges);

  agg_kernel<<<wb, 256, 0, stream>>>(h, row_ptr, edata, h_agg, n_nodes);
  softmax_kernel<<<wb, 256, 0, stream>>>(h_agg, row_ptr, edata, e_soft, n_nodes);
}

// Round 6
// 422.011 us; speedup vs baseline: 1.1777x; 1.1777x over previous
//
#include <hip/hip_runtime.h>
#include <math.h>

#define IN_FEATS 128
#define OUT_FEATS 64
#define NEG_SLOPE 0.2f
#define MAXD 256

// ---------------------------------------------------------------------------
// K1: h[n][o] = sum_k feat[n][k] * W[o][k]
// Lane-per-output: lane o holds W[o][:] in 128 VGPRs, loaded ONCE per block.
// 1-wave blocks + __launch_bounds__(64,1) -> VGPR budget up to 512, no spill
// (R1's version of this spilled because the default cap was 64 VGPRs).
// n is block-uniform -> feat row goes on the scalar path (s_load), shared by
// all 64 lanes as the 1-SGPR operand of v_fmac. Zero W traffic per node.
// ---------------------------------------------------------------------------
__global__ __launch_bounds__(64, 1)
void gemm_h_kernel(const float* __restrict__ feat,
                   const float* __restrict__ W,
                   float* __restrict__ h, int n_nodes) {
  const int lane = threadIdx.x;  // 0..63 = output index

  float4 w[32];
  const float4* Wv = reinterpret_cast<const float4*>(W + (size_t)lane * IN_FEATS);
#pragma unroll
  for (int i = 0; i < 32; ++i) w[i] = Wv[i];

  for (int n = blockIdx.x; n < n_nodes; n += gridDim.x) {
    const float4* fv = reinterpret_cast<const float4*>(feat + (size_t)n * IN_FEATS);
    float acc = 0.f;
#pragma unroll
    for (int c = 0; c < 4; ++c) {
      float4 f[8];
#pragma unroll
      for (int j = 0; j < 8; ++j) f[j] = fv[c * 8 + j];
#pragma unroll
      for (int j = 0; j < 8; ++j) {
        acc = fmaf(f[j].x, w[c * 8 + j].x, acc);
        acc = fmaf(f[j].y, w[c * 8 + j].y, acc);
        acc = fmaf(f[j].z, w[c * 8 + j].z, acc);
        acc = fmaf(f[j].w, w[c * 8 + j].w, acc);
      }
    }
    h[(size_t)n * OUT_FEATS + lane] = acc;
  }
}

// ---------------------------------------------------------------------------
// CSR build: histogram -> 3-kernel exclusive scan -> bin (packed int2)
// ---------------------------------------------------------------------------
__global__ void hist_kernel(const int* __restrict__ dst, int* __restrict__ deg,
                            int n_edges) {
  int e = blockIdx.x * blockDim.x + threadIdx.x;
  if (e < n_edges) atomicAdd(&deg[dst[e]], 1);
}

__global__ void scan1_kernel(const int* __restrict__ deg, int* __restrict__ bsum,
                             int n) {
  __shared__ int tmp[256];
  int i = blockIdx.x * 256 + threadIdx.x;
  tmp[threadIdx.x] = (i < n) ? deg[i] : 0;
  __syncthreads();
  for (int off = 128; off > 0; off >>= 1) {
    if (threadIdx.x < off) tmp[threadIdx.x] += tmp[threadIdx.x + off];
    __syncthreads();
  }
  if (threadIdx.x == 0) bsum[blockIdx.x] = tmp[0];
}

__global__ void scan2_kernel(int* __restrict__ bsum, int nb) {
  __shared__ int tmp[1024];
  int t = threadIdx.x;
  int v = (t < nb) ? bsum[t] : 0;
  tmp[t] = v;
  __syncthreads();
  for (int off = 1; off < 1024; off <<= 1) {
    int x = (t >= off) ? tmp[t - off] : 0;
    __syncthreads();
    tmp[t] += x;
    __syncthreads();
  }
  if (t < nb) bsum[t] = tmp[t] - v;  // exclusive
}

__global__ void scan3_kernel(const int* __restrict__ deg, const int* __restrict__ bsum,
                             int* __restrict__ row_ptr, int* __restrict__ cursor,
                             int n, int n_edges) {
  __shared__ int tmp[256];
  int i = blockIdx.x * 256 + threadIdx.x;
  int v = (i < n) ? deg[i] : 0;
  tmp[threadIdx.x] = v;
  __syncthreads();
  for (int off = 1; off < 256; off <<= 1) {
    int x = (threadIdx.x >= off) ? tmp[threadIdx.x - off] : 0;
    __syncthreads();
    tmp[threadIdx.x] += x;
    __syncthreads();
  }
  if (i < n) {
    int excl = tmp[threadIdx.x] - v + bsum[blockIdx.x];
    row_ptr[i] = excl;
    cursor[i]  = excl;
  }
  if (i == 0) row_ptr[n] = n_edges;
}

__global__ void bin_kernel(const int* __restrict__ src, const int* __restrict__ dst,
                           int* __restrict__ cursor, int2* __restrict__ edata,
                           int n_edges) {
  int e = blockIdx.x * blockDim.x + threadIdx.x;
  if (e < n_edges) {
    int d = dst[e];
    int pos = atomicAdd(&cursor[d], 1);
    int2 v; v.x = src[e]; v.y = e;
    edata[pos] = v;
  }
}

// ---------------------------------------------------------------------------
// agg: wave per node, 4 edges in flight (lane = 16*eo + fo, float4 per lane)
// ---------------------------------------------------------------------------
__global__ void agg_kernel(const float* __restrict__ h, const int* __restrict__ row_ptr,
                           const int2* __restrict__ edata, float* __restrict__ h_agg,
                           int n_nodes) {
  int wid  = (blockIdx.x * blockDim.x + threadIdx.x) >> 6;
  int lane = threadIdx.x & 63;
  int eo = lane >> 4;   // edge slot in group of 4
  int fo = lane & 15;   // float4 slot in row
  if (wid >= n_nodes) return;
  int beg = row_ptr[wid], end = row_ptr[wid + 1];
  float4 acc = {0.f, 0.f, 0.f, 0.f};
  for (int i = beg + eo; i < end; i += 4) {
    int s = edata[i].x;
    float4 v = *reinterpret_cast<const float4*>(h + (size_t)s * OUT_FEATS + fo * 4);
    acc.x += v.x; acc.y += v.y; acc.z += v.z; acc.w += v.w;
  }
#pragma unroll
  for (int off = 16; off < 64; off <<= 1) {
    acc.x += __shfl_xor(acc.x, off, 64);
    acc.y += __shfl_xor(acc.y, off, 64);
    acc.z += __shfl_xor(acc.z, off, 64);
    acc.w += __shfl_xor(acc.w, off, 64);
  }
  if (eo == 0)
    *reinterpret_cast<float4*>(h_agg + (size_t)wid * OUT_FEATS + fo * 4) = acc;
}

// ---------------------------------------------------------------------------
// fused per-node edge softmax, 4 edges in flight.
// ---------------------------------------------------------------------------
__global__ __launch_bounds__(256)
void softmax_kernel(const float* __restrict__ h_agg, const int* __restrict__ row_ptr,
                    const int2* __restrict__ edata,
                    float* __restrict__ e_soft, int n_nodes) {
  __shared__ float ebuf[4][MAXD];
  int wid  = (blockIdx.x * blockDim.x + threadIdx.x) >> 6;
  int lane = threadIdx.x & 63;
  int lw   = threadIdx.x >> 6;
  int eo = lane >> 4;
  int fo = lane & 15;
  if (wid >= n_nodes) return;
  int beg = row_ptr[wid], end = row_ptr[wid + 1];
  int deg = end - beg;
  if (deg == 0) return;

  float4 td = *reinterpret_cast<const float4*>(h_agg + (size_t)wid * OUT_FEATS + fo * 4);
  float4 t4;
  t4.x = tanhf(td.x); t4.y = tanhf(td.y); t4.z = tanhf(td.z); t4.w = tanhf(td.w);

  if (deg <= MAXD) {
    for (int i0 = 0; i0 < deg; i0 += 4) {
      int e = i0 + eo;
      int idx = beg + (e < deg ? e : deg - 1);  // clamp; dup gather harmless
      int s = edata[idx].x;
      float4 v = *reinterpret_cast<const float4*>(h_agg + (size_t)s * OUT_FEATS + fo * 4);
      float d = v.x * t4.x + v.y * t4.y + v.z * t4.z + v.w * t4.w;
#pragma unroll
      for (int off = 1; off < 16; off <<= 1) d += __shfl_xor(d, off, 64);
      if (fo == 0 && e < deg) {
        d = d > 0.f ? d : NEG_SLOPE * d;
        ebuf[lw][e] = d;
      }
    }
    float mx = -INFINITY;
    for (int i = lane; i < deg; i += 64) mx = fmaxf(mx, ebuf[lw][i]);
#pragma unroll
    for (int off = 32; off > 0; off >>= 1) mx = fmaxf(mx, __shfl_xor(mx, off, 64));
    float sum = 0.f;
    for (int i = lane; i < deg; i += 64) {
      float ex = expf(ebuf[lw][i] - mx);
      ebuf[lw][i] = ex;
      sum += ex;
    }
#pragma unroll
    for (int off = 32; off > 0; off >>= 1) sum += __shfl_xor(sum, off, 64);
    float inv = 1.f / sum;
    for (int i = lane; i < deg; i += 64) e_soft[edata[beg + i].y] = ebuf[lw][i] * inv;
  } else {
    // recompute fallback (statistically never hit with Poisson(16) degrees)
    float mx = -INFINITY;
    for (int i0 = 0; i0 < deg; i0 += 4) {
      int e = i0 + eo;
      int idx = beg + (e < deg ? e : deg - 1);
      int s = edata[idx].x;
      float4 v = *reinterpret_cast<const float4*>(h_agg + (size_t)s * OUT_FEATS + fo * 4);
      float d = v.x * t4.x + v.y * t4.y + v.z * t4.z + v.w * t4.w;
#pragma unroll
      for (int off = 1; off < 16; off <<= 1) d += __shfl_xor(d, off, 64);
      d = d > 0.f ? d : NEG_SLOPE * d;
      if (e >= deg) d = -INFINITY;
#pragma unroll
      for (int off = 16; off < 64; off <<= 1) d = fmaxf(d, __shfl_xor(d, off, 64));
      mx = fmaxf(mx, d);
    }
    float sum = 0.f;
    for (int i0 = 0; i0 < deg; i0 += 4) {
      int e = i0 + eo;
      int idx = beg + (e < deg ? e : deg - 1);
      int s = edata[idx].x;
      float4 v = *reinterpret_cast<const float4*>(h_agg + (size_t)s * OUT_FEATS + fo * 4);
      float d = v.x * t4.x + v.y * t4.y + v.z * t4.z + v.w * t4.w;
#pragma unroll
      for (int off = 1; off < 16; off <<= 1) d += __shfl_xor(d, off, 64);
      d = d > 0.f ? d : NEG_SLOPE * d;
      float ex = (e < deg) ? expf(d - mx) : 0.f;
#pragma unroll
      for (int off = 16; off < 64; off <<= 1) ex += __shfl_xor(ex, off, 64);
      sum += ex;
    }
    float inv = 1.f / sum;
    for (int i0 = 0; i0 < deg; i0 += 4) {
      int e = i0 + eo;
      int idx = beg + (e < deg ? e : deg - 1);
      int s = edata[idx].x;
      float4 v = *reinterpret_cast<const float4*>(h_agg + (size_t)s * OUT_FEATS + fo * 4);
      float d = v.x * t4.x + v.y * t4.y + v.z * t4.z + v.w * t4.w;
#pragma unroll
      for (int off = 1; off < 16; off <<= 1) d += __shfl_xor(d, off, 64);
      d = d > 0.f ? d : NEG_SLOPE * d;
      if (fo == 0 && e < deg) e_soft[edata[idx].y] = expf(d - mx) * inv;
    }
  }
}

extern "C" void kernel_launch(void* const* d_in, const int* in_sizes, int n_in,
                              void* d_out, int out_size, void* d_ws, size_t ws_size,
                              hipStream_t stream) {
  const float* feat = (const float*)d_in[0];
  const float* W    = (const float*)d_in[1];
  const int*   src  = (const int*)d_in[2];
  const int*   dst  = (const int*)d_in[3];
  const int n_nodes = in_sizes[0] / IN_FEATS;
  const int n_edges = in_sizes[2];

  // Output layout: [h_agg (N*64) | e_soft (E)]
  float* h_agg  = (float*)d_out;
  float* e_soft = (float*)d_out + (size_t)n_nodes * OUT_FEATS;

  // Workspace: [h (N*64 f32) | deg (N) | row_ptr (N+1) | cursor (N) | bsum (1024) | edata (2*E ints)]
  float* h      = (float*)d_ws;
  int* deg      = (int*)(h + (size_t)n_nodes * OUT_FEATS);
  int* row_ptr  = deg + n_nodes;
  int* cursor   = row_ptr + (n_nodes + 1);
  int* bsum     = cursor + n_nodes;
  int2* edata   = (int2*)(bsum + 1024);

  const int nb = (n_nodes + 255) / 256;   // 391 blocks; scan2 handles nb<=1024
  const int eb = (n_edges + 255) / 256;
  const int wb = (n_nodes * 64 + 255) / 256;  // wave-per-node grids

  hipMemsetAsync(deg, 0, (size_t)n_nodes * sizeof(int), stream);

  // gemm: 1-wave blocks, grid-stride; 3072 = 12 blocks/CU at 3 waves/SIMD
  gemm_h_kernel<<<3072, 64, 0, stream>>>(feat, W, h, n_nodes);

  hist_kernel<<<eb, 256, 0, stream>>>(dst, deg, n_edges);
  scan1_kernel<<<nb, 256, 0, stream>>>(deg, bsum, n_nodes);
  scan2_kernel<<<1, 1024, 0, stream>>>(bsum, nb);
  scan3_kernel<<<nb, 256, 0, stream>>>(deg, bsum, row_ptr, cursor, n_nodes, n_edges);
  bin_kernel<<<eb, 256, 0, stream>>>(src, dst, cursor, edata, n_edges);

  agg_kernel<<<wb, 256, 0, stream>>>(h, row_ptr, edata, h_agg, n_nodes);
  softmax_kernel<<<wb, 256, 0, stream>>>(h_agg, row_ptr, edata, e_soft, n_nodes);
}

// Round 7
// 288.037 us; speedup vs baseline: 1.7255x; 1.4651x over previous
//
#include <hip/hip_runtime.h>
#include <math.h>

#define IN_FEATS 128
#define OUT_FEATS 64
#define NEG_SLOPE 0.2f
#define MAXD 256
#define BSH 8                      // bucket = dst >> 8 (256 nodes/bucket)
#define BNODES (1 << BSH)
#define CHUNK 4096                 // edges per block in bucket passes
#define EPT 16                     // edges per thread (CHUNK/256)
#define EID_BITS 21                // n_edges < 2^21

// ---------------------------------------------------------------------------
// K1: h[n][o] = sum_k feat[n][k] * W[o][k]
// Lane-per-output, 1-wave blocks; W in 128 VGPRs loaded once per block;
// feat row block-uniform -> scalar path.
// ---------------------------------------------------------------------------
__global__ __launch_bounds__(64, 1)
void gemm_h_kernel(const float* __restrict__ feat,
                   const float* __restrict__ W,
                   float* __restrict__ h, int n_nodes) {
  const int lane = threadIdx.x;  // 0..63 = output index

  float4 w[32];
  const float4* Wv = reinterpret_cast<const float4*>(W + (size_t)lane * IN_FEATS);
#pragma unroll
  for (int i = 0; i < 32; ++i) w[i] = Wv[i];

  for (int n = blockIdx.x; n < n_nodes; n += gridDim.x) {
    const float4* fv = reinterpret_cast<const float4*>(feat + (size_t)n * IN_FEATS);
    float acc = 0.f;
#pragma unroll
    for (int c = 0; c < 4; ++c) {
      float4 f[8];
#pragma unroll
      for (int j = 0; j < 8; ++j) f[j] = fv[c * 8 + j];
#pragma unroll
      for (int j = 0; j < 8; ++j) {
        acc = fmaf(f[j].x, w[c * 8 + j].x, acc);
        acc = fmaf(f[j].y, w[c * 8 + j].y, acc);
        acc = fmaf(f[j].z, w[c * 8 + j].z, acc);
        acc = fmaf(f[j].w, w[c * 8 + j].w, acc);
      }
    }
    h[(size_t)n * OUT_FEATS + lane] = acc;
  }
}

// ---------------------------------------------------------------------------
// Bucket sort pass A1: per-bucket edge counts (LDS hist, one flush per block)
// ---------------------------------------------------------------------------
__global__ __launch_bounds__(256)
void bhist_kernel(const int* __restrict__ dst, int* __restrict__ bcount,
                  int n_edges, int nbuck) {
  __shared__ int hist[512];
  const int t = threadIdx.x;
  for (int i = t; i < nbuck; i += 256) hist[i] = 0;
  __syncthreads();
  const int base = blockIdx.x * CHUNK;
#pragma unroll
  for (int i = 0; i < EPT; ++i) {
    int e = base + t + i * 256;
    if (e < n_edges) atomicAdd(&hist[dst[e] >> BSH], 1);
  }
  __syncthreads();
  for (int i = t; i < nbuck; i += 256)
    if (hist[i]) atomicAdd(&bcount[i], hist[i]);
}

// ---------------------------------------------------------------------------
// A2: exclusive scan of bucket counts (single block, nbuck <= 512)
// ---------------------------------------------------------------------------
__global__ void bscan_kernel(const int* __restrict__ bcount, int* __restrict__ bbase,
                             int* __restrict__ bcursor, int nbuck, int n_edges) {
  __shared__ int tmp[512];
  const int t = threadIdx.x;
  int v = (t < nbuck) ? bcount[t] : 0;
  tmp[t] = v;
  __syncthreads();
  for (int off = 1; off < 512; off <<= 1) {
    int x = (t >= off) ? tmp[t - off] : 0;
    __syncthreads();
    tmp[t] += x;
    __syncthreads();
  }
  if (t < nbuck) { int excl = tmp[t] - v; bbase[t] = excl; bcursor[t] = excl; }
  if (t == 0) bbase[nbuck] = n_edges;
}

// ---------------------------------------------------------------------------
// A3: scatter edges into bucket regions. Per-block LDS hist -> one global
// atomicAdd per (block,bucket) reserves a contiguous chunk -> writes land in
// ~16-edge contiguous runs instead of 1 random line per edge.
// Record: (src, dstLow8 << 21 | eid)
// ---------------------------------------------------------------------------
__global__ __launch_bounds__(256)
void bscatter_kernel(const int* __restrict__ src, const int* __restrict__ dst,
                     int* __restrict__ bcursor, int2* __restrict__ tmpe,
                     int n_edges, int nbuck) {
  __shared__ int hist[512];
  __shared__ int basech[512];
  __shared__ int offs[512];
  const int t = threadIdx.x;
  const int base = blockIdx.x * CHUNK;
  for (int i = t; i < nbuck; i += 256) { hist[i] = 0; offs[i] = 0; }
  __syncthreads();
  int s16[EPT], d16[EPT];
#pragma unroll
  for (int i = 0; i < EPT; ++i) {
    int e = base + t + i * 256;
    if (e < n_edges) {
      s16[i] = src[e];
      d16[i] = dst[e];
      atomicAdd(&hist[d16[i] >> BSH], 1);
    } else {
      d16[i] = -1;
    }
  }
  __syncthreads();
  for (int i = t; i < nbuck; i += 256)
    if (hist[i]) basech[i] = atomicAdd(&bcursor[i], hist[i]);
  __syncthreads();
#pragma unroll
  for (int i = 0; i < EPT; ++i) {
    if (d16[i] >= 0) {
      int e = base + t + i * 256;
      int b = d16[i] >> BSH;
      int off = atomicAdd(&offs[b], 1);
      int2 v;
      v.x = s16[i];
      v.y = ((d16[i] & (BNODES - 1)) << EID_BITS) | e;
      tmpe[basech[b] + off] = v;
    }
  }
}

// ---------------------------------------------------------------------------
// B: one workgroup per bucket. LDS per-node counts -> LDS scan -> row_ptr
// (replaces hist/scan1/scan2/scan3) -> scatter (src,eid) into final CSR
// region (contiguous ~32KB window, L2-local).
// ---------------------------------------------------------------------------
__global__ __launch_bounds__(256)
void binB_kernel(const int2* __restrict__ tmpe, const int* __restrict__ bbase,
                 int2* __restrict__ edata, int* __restrict__ row_ptr,
                 int n_nodes, int n_edges) {
  __shared__ int cnt[BNODES];
  __shared__ int cur[BNODES];
  const int b = blockIdx.x;
  const int t = threadIdx.x;
  const int beg = bbase[b], end = bbase[b + 1];

  cnt[t] = 0;
  __syncthreads();
  for (int i = beg + t; i < end; i += 256)
    atomicAdd(&cnt[(tmpe[i].y >> EID_BITS) & (BNODES - 1)], 1);
  __syncthreads();

  // exclusive scan of cnt (Hillis-Steele)
  int v = cnt[t];
  cur[t] = v;
  __syncthreads();
  for (int off = 1; off < BNODES; off <<= 1) {
    int x = (t >= off) ? cur[t - off] : 0;
    __syncthreads();
    cur[t] += x;
    __syncthreads();
  }
  int excl = cur[t] - v;
  int node = b * BNODES + t;
  if (node < n_nodes) row_ptr[node] = beg + excl;
  if (b == 0 && t == 0) row_ptr[n_nodes] = n_edges;
  __syncthreads();
  cur[t] = beg + excl;
  __syncthreads();

  for (int i = beg + t; i < end; i += 256) {
    int2 p = tmpe[i];
    int l = (p.y >> EID_BITS) & (BNODES - 1);
    int pos = atomicAdd(&cur[l], 1);
    int2 o;
    o.x = p.x;
    o.y = p.y & ((1 << EID_BITS) - 1);
    edata[pos] = o;
  }
}

// ---------------------------------------------------------------------------
// agg: wave per node, 4 edges in flight (lane = 16*eo + fo, float4 per lane)
// ---------------------------------------------------------------------------
__global__ void agg_kernel(const float* __restrict__ h, const int* __restrict__ row_ptr,
                           const int2* __restrict__ edata, float* __restrict__ h_agg,
                           int n_nodes) {
  int wid  = (blockIdx.x * blockDim.x + threadIdx.x) >> 6;
  int lane = threadIdx.x & 63;
  int eo = lane >> 4;   // edge slot in group of 4
  int fo = lane & 15;   // float4 slot in row
  if (wid >= n_nodes) return;
  int beg = row_ptr[wid], end = row_ptr[wid + 1];
  float4 acc = {0.f, 0.f, 0.f, 0.f};
  for (int i = beg + eo; i < end; i += 4) {
    int s = edata[i].x;
    float4 v = *reinterpret_cast<const float4*>(h + (size_t)s * OUT_FEATS + fo * 4);
    acc.x += v.x; acc.y += v.y; acc.z += v.z; acc.w += v.w;
  }
#pragma unroll
  for (int off = 16; off < 64; off <<= 1) {
    acc.x += __shfl_xor(acc.x, off, 64);
    acc.y += __shfl_xor(acc.y, off, 64);
    acc.z += __shfl_xor(acc.z, off, 64);
    acc.w += __shfl_xor(acc.w, off, 64);
  }
  if (eo == 0)
    *reinterpret_cast<float4*>(h_agg + (size_t)wid * OUT_FEATS + fo * 4) = acc;
}

// ---------------------------------------------------------------------------
// fused per-node edge softmax, 4 edges in flight.
// ---------------------------------------------------------------------------
__global__ __launch_bounds__(256)
void softmax_kernel(const float* __restrict__ h_agg, const int* __restrict__ row_ptr,
                    const int2* __restrict__ edata,
                    float* __restrict__ e_soft, int n_nodes) {
  __shared__ float ebuf[4][MAXD];
  int wid  = (blockIdx.x * blockDim.x + threadIdx.x) >> 6;
  int lane = threadIdx.x & 63;
  int lw   = threadIdx.x >> 6;
  int eo = lane >> 4;
  int fo = lane & 15;
  if (wid >= n_nodes) return;
  int beg = row_ptr[wid], end = row_ptr[wid + 1];
  int deg = end - beg;
  if (deg == 0) return;

  float4 td = *reinterpret_cast<const float4*>(h_agg + (size_t)wid * OUT_FEATS + fo * 4);
  float4 t4;
  t4.x = tanhf(td.x); t4.y = tanhf(td.y); t4.z = tanhf(td.z); t4.w = tanhf(td.w);

  if (deg <= MAXD) {
    for (int i0 = 0; i0 < deg; i0 += 4) {
      int e = i0 + eo;
      int idx = beg + (e < deg ? e : deg - 1);  // clamp; dup gather harmless
      int s = edata[idx].x;
      float4 v = *reinterpret_cast<const float4*>(h_agg + (size_t)s * OUT_FEATS + fo * 4);
      float d = v.x * t4.x + v.y * t4.y + v.z * t4.z + v.w * t4.w;
#pragma unroll
      for (int off = 1; off < 16; off <<= 1) d += __shfl_xor(d, off, 64);
      if (fo == 0 && e < deg) {
        d = d > 0.f ? d : NEG_SLOPE * d;
        ebuf[lw][e] = d;
      }
    }
    float mx = -INFINITY;
    for (int i = lane; i < deg; i += 64) mx = fmaxf(mx, ebuf[lw][i]);
#pragma unroll
    for (int off = 32; off > 0; off >>= 1) mx = fmaxf(mx, __shfl_xor(mx, off, 64));
    float sum = 0.f;
    for (int i = lane; i < deg; i += 64) {
      float ex = expf(ebuf[lw][i] - mx);
      ebuf[lw][i] = ex;
      sum += ex;
    }
#pragma unroll
    for (int off = 32; off > 0; off >>= 1) sum += __shfl_xor(sum, off, 64);
    float inv = 1.f / sum;
    for (int i = lane; i < deg; i += 64) e_soft[edata[beg + i].y] = ebuf[lw][i] * inv;
  } else {
    // recompute fallback (statistically never hit with Poisson(16) degrees)
    float mx = -INFINITY;
    for (int i0 = 0; i0 < deg; i0 += 4) {
      int e = i0 + eo;
      int idx = beg + (e < deg ? e : deg - 1);
      int s = edata[idx].x;
      float4 v = *reinterpret_cast<const float4*>(h_agg + (size_t)s * OUT_FEATS + fo * 4);
      float d = v.x * t4.x + v.y * t4.y + v.z * t4.z + v.w * t4.w;
#pragma unroll
      for (int off = 1; off < 16; off <<= 1) d += __shfl_xor(d, off, 64);
      d = d > 0.f ? d : NEG_SLOPE * d;
      if (e >= deg) d = -INFINITY;
#pragma unroll
      for (int off = 16; off < 64; off <<= 1) d = fmaxf(d, __shfl_xor(d, off, 64));
      mx = fmaxf(mx, d);
    }
    float sum = 0.f;
    for (int i0 = 0; i0 < deg; i0 += 4) {
      int e = i0 + eo;
      int idx = beg + (e < deg ? e : deg - 1);
      int s = edata[idx].x;
      float4 v = *reinterpret_cast<const float4*>(h_agg + (size_t)s * OUT_FEATS + fo * 4);
      float d = v.x * t4.x + v.y * t4.y + v.z * t4.z + v.w * t4.w;
#pragma unroll
      for (int off = 1; off < 16; off <<= 1) d += __shfl_xor(d, off, 64);
      d = d > 0.f ? d : NEG_SLOPE * d;
      float ex = (e < deg) ? expf(d - mx) : 0.f;
#pragma unroll
      for (int off = 16; off < 64; off <<= 1) ex += __shfl_xor(ex, off, 64);
      sum += ex;
    }
    float inv = 1.f / sum;
    for (int i0 = 0; i0 < deg; i0 += 4) {
      int e = i0 + eo;
      int idx = beg + (e < deg ? e : deg - 1);
      int s = edata[idx].x;
      float4 v = *reinterpret_cast<const float4*>(h_agg + (size_t)s * OUT_FEATS + fo * 4);
      float d = v.x * t4.x + v.y * t4.y + v.z * t4.z + v.w * t4.w;
#pragma unroll
      for (int off = 1; off < 16; off <<= 1) d += __shfl_xor(d, off, 64);
      d = d > 0.f ? d : NEG_SLOPE * d;
      if (fo == 0 && e < deg) e_soft[edata[idx].y] = expf(d - mx) * inv;
    }
  }
}

extern "C" void kernel_launch(void* const* d_in, const int* in_sizes, int n_in,
                              void* d_out, int out_size, void* d_ws, size_t ws_size,
                              hipStream_t stream) {
  const float* feat = (const float*)d_in[0];
  const float* W    = (const float*)d_in[1];
  const int*   src  = (const int*)d_in[2];
  const int*   dst  = (const int*)d_in[3];
  const int n_nodes = in_sizes[0] / IN_FEATS;
  const int n_edges = in_sizes[2];
  const int nbuck   = (n_nodes + BNODES - 1) >> BSH;   // <= 512

  // Output layout: [h_agg (N*64) | e_soft (E)]
  float* h_agg  = (float*)d_out;
  float* e_soft = (float*)d_out + (size_t)n_nodes * OUT_FEATS;

  // Workspace:
  // [h (N*64 f32) | bcount(513) | bbase(513) | bcursor(512) | row_ptr(N+1, pad even)
  //  | tmpe (E int2) | edata (E int2)]
  float* h      = (float*)d_ws;
  int* bcount   = (int*)(h + (size_t)n_nodes * OUT_FEATS);
  int* bbase    = bcount + 513;
  int* bcursor  = bbase + 513;
  int* row_ptr  = bcursor + 512;
  size_t rp_pad = ((size_t)n_nodes + 2) & ~(size_t)1;  // keep int2 8B-aligned
  int2* tmpe    = (int2*)(row_ptr + rp_pad);
  int2* edata   = tmpe + n_edges;

  const int eb2 = (n_edges + CHUNK - 1) / CHUNK;       // 391 blocks
  const int wb  = (n_nodes * 64 + 255) / 256;          // wave-per-node grids

  hipMemsetAsync(bcount, 0, (size_t)nbuck * sizeof(int), stream);

  gemm_h_kernel<<<3072, 64, 0, stream>>>(feat, W, h, n_nodes);

  bhist_kernel<<<eb2, 256, 0, stream>>>(dst, bcount, n_edges, nbuck);
  bscan_kernel<<<1, 512, 0, stream>>>(bcount, bbase, bcursor, nbuck, n_edges);
  bscatter_kernel<<<eb2, 256, 0, stream>>>(src, dst, bcursor, tmpe, n_edges, nbuck);
  binB_kernel<<<nbuck, 256, 0, stream>>>(tmpe, bbase, edata, row_ptr, n_nodes, n_edges);

  agg_kernel<<<wb, 256, 0, stream>>>(h, row_ptr, edata, h_agg, n_nodes);
  softmax_kernel<<<wb, 256, 0, stream>>>(h_agg, row_ptr, edata, e_soft, n_nodes);
}